// Round 10
// baseline (201.552 us; speedup 1.0000x reference)
//
#include <hip/hip_runtime.h>
#include <hip/hip_bf16.h>

typedef __bf16 bf16_t;
typedef __bf16 bf16x8 __attribute__((ext_vector_type(8)));
typedef __bf16 bf16x4 __attribute__((ext_vector_type(4)));
typedef float f32x4 __attribute__((ext_vector_type(4)));

#define FDIM 512
#define BM 32
#define NTHR 512
#define TILES 16
#define NBLK 256   // 1 block/CU, persistent; 131072 rows / 32 / 16 = 256

// Kernel 1: Qt[g][f] = bf16(Q[f][g]) via LDS-tiled transpose
__global__ void qtrans_kernel(const float* __restrict__ Q, bf16_t* __restrict__ Qt) {
    __shared__ float t[32][33];
    int tx = threadIdx.x & 31;
    int ty = threadIdx.x >> 5;
    int f0 = blockIdx.x * 32;
    int g0 = blockIdx.y * 32;
#pragma unroll
    for (int i = 0; i < 4; ++i)
        t[ty + 8 * i][tx] = Q[(size_t)(f0 + ty + 8 * i) * FDIM + g0 + tx];
    __syncthreads();
#pragma unroll
    for (int i = 0; i < 4; ++i)
        Qt[(size_t)(g0 + ty + 8 * i) * FDIM + f0 + tx] = (bf16_t)t[tx][ty + 8 * i];
}

// Kernel 2: out[b] = sum_g (x Q)[b,g] * x[b,g]
// PERSISTENT design: 256 blocks (1/CU) x 512 thr (8 waves), 16 tiles of 32
// rows each. Each wave holds ALL its Qt B-fragments in registers (34 bf16x8 =
// 136 VGPRs), loaded once -> inner loop is pure LDS+MFMA, no global loads.
// Triangle via static slot remap: slot kk in [0,17): kk<=w -> (pair w, ks=kk),
// else (pair 15-w, ks=kk-w-1). All register indices compile-time.
// x double-buffered in LDS (2x32KB); next tile streamed global->reg->LDS
// mid-compute (2 batches of 4 float4, <=16 regs held).
__global__ __launch_bounds__(NTHR, 2) void bilinear_kernel(
    const float* __restrict__ x, const bf16_t* __restrict__ Qt,
    float* __restrict__ out)
{
    __shared__ bf16_t xs[2][BM * FDIM];   // 2 x 32 KB, swizzle: e ^= (row&15)<<3
    __shared__ float rsum[8][BM];

    const int tid = threadIdx.x;
    const int w   = tid >> 6;
    const int l   = tid & 63;
    const int col = l & 15;
    const int kg  = l >> 4;

    // ---- B prologue: 34 fragments into registers (static indices) ----
    bf16x8 B[34];
#pragma unroll
    for (int kk = 0; kk < 17; ++kk) {
        const int p  = (kk <= w) ? w : (15 - w);
        const int ks = (kk <= w) ? kk : (kk - w - 1);
        const bf16_t* q0 = Qt + (size_t)(p * 32 + col) * FDIM + ks * 32 + kg * 8;
        B[2 * kk]     = *(const bf16x8*)(q0);
        B[2 * kk + 1] = *(const bf16x8*)(q0 + 16 * FDIM);
    }

    // ---- stage tile 0 into xs[0] (2 batches of 4 float4) ----
    {
        const float4* xin = (const float4*)(x + (size_t)blockIdx.x * TILES * BM * FDIM);
#pragma unroll 1
        for (int it = 0; it < 2; ++it) {
            float4 vv[4];
#pragma unroll
            for (int j = 0; j < 4; ++j) vv[j] = xin[(it * 4 + j) * NTHR + tid];
#pragma unroll
            for (int j = 0; j < 4; ++j) {
                int e = ((it * 4 + j) * NTHR + tid) * 4;
                int row = e >> 9;
                int se = e ^ ((row & 15) << 3);
                bf16x4 b;
                b[0] = (bf16_t)vv[j].x; b[1] = (bf16_t)vv[j].y;
                b[2] = (bf16_t)vv[j].z; b[3] = (bf16_t)vv[j].w;
                *(bf16x4*)(&xs[0][0] + se) = b;
            }
            __builtin_amdgcn_sched_barrier(0);
        }
    }
    __syncthreads();

    const int rb0 = col * FDIM + kg * 8;           // A row = col      (m=0)
    const int rb1 = (16 + col) * FDIM + kg * 8;    // A row = 16+col   (m=1)
    const int amask = col << 3;

#pragma unroll 1
    for (int t = 0; t < TILES; ++t) {
        const int buf = t & 1;
        const size_t row0 = ((size_t)blockIdx.x * TILES + t) * BM;
        const bool pf = (t + 1 < TILES);
        const float4* xnext = (const float4*)(x + (row0 + BM) * FDIM);
        bf16_t* xw = &xs[buf ^ 1][0];
        const bf16_t* xr = &xs[buf][0];

        // issue batch 0 of next tile's loads (held in 16 regs)
        float4 f[4];
        if (pf) {
#pragma unroll
            for (int j = 0; j < 4; ++j) f[j] = xnext[j * NTHR + tid];
        }
        __builtin_amdgcn_sched_barrier(0);

        f32x4 acc[2][2][2];   // [pair][16-col half][row-tile]
#pragma unroll
        for (int pi = 0; pi < 2; ++pi)
#pragma unroll
            for (int h = 0; h < 2; ++h)
#pragma unroll
                for (int m = 0; m < 2; ++m)
#pragma unroll
                    for (int j = 0; j < 4; ++j) acc[pi][h][m][j] = 0.0f;

        // ---- 17 static slots: pure ds_read + MFMA (B from registers) ----
#pragma unroll
        for (int kk = 0; kk < 17; ++kk) {
            const int ks = (kk <= w) ? kk : (kk - w - 1);
            bf16x8 a0 = *(const bf16x8*)(xr + ((rb0 + ks * 32) ^ amask));
            bf16x8 a1 = *(const bf16x8*)(xr + ((rb1 + ks * 32) ^ amask));
            if (kk <= w) {
                acc[0][0][0] = __builtin_amdgcn_mfma_f32_16x16x32_bf16(a0, B[2*kk],   acc[0][0][0], 0, 0, 0);
                acc[0][0][1] = __builtin_amdgcn_mfma_f32_16x16x32_bf16(a1, B[2*kk],   acc[0][0][1], 0, 0, 0);
                acc[0][1][0] = __builtin_amdgcn_mfma_f32_16x16x32_bf16(a0, B[2*kk+1], acc[0][1][0], 0, 0, 0);
                acc[0][1][1] = __builtin_amdgcn_mfma_f32_16x16x32_bf16(a1, B[2*kk+1], acc[0][1][1], 0, 0, 0);
            } else {
                acc[1][0][0] = __builtin_amdgcn_mfma_f32_16x16x32_bf16(a0, B[2*kk],   acc[1][0][0], 0, 0, 0);
                acc[1][0][1] = __builtin_amdgcn_mfma_f32_16x16x32_bf16(a1, B[2*kk],   acc[1][0][1], 0, 0, 0);
                acc[1][1][0] = __builtin_amdgcn_mfma_f32_16x16x32_bf16(a0, B[2*kk+1], acc[1][1][0], 0, 0, 0);
                acc[1][1][1] = __builtin_amdgcn_mfma_f32_16x16x32_bf16(a1, B[2*kk+1], acc[1][1][1], 0, 0, 0);
            }
            // mid-compute staging: write batch 0, issue batch 1; write batch 1
            if (kk == 7 && pf) {
#pragma unroll
                for (int j = 0; j < 4; ++j) {
                    int e = (j * NTHR + tid) * 4;
                    int row = e >> 9;
                    int se = e ^ ((row & 15) << 3);
                    bf16x4 b;
                    b[0] = (bf16_t)f[j].x; b[1] = (bf16_t)f[j].y;
                    b[2] = (bf16_t)f[j].z; b[3] = (bf16_t)f[j].w;
                    *(bf16x4*)(xw + se) = b;
                }
#pragma unroll
                for (int j = 0; j < 4; ++j) f[j] = xnext[(4 + j) * NTHR + tid];
                __builtin_amdgcn_sched_barrier(0);
            }
            if (kk == 15 && pf) {
#pragma unroll
                for (int j = 0; j < 4; ++j) {
                    int e = ((4 + j) * NTHR + tid) * 4;
                    int row = e >> 9;
                    int se = e ^ ((row & 15) << 3);
                    bf16x4 b;
                    b[0] = (bf16_t)f[j].x; b[1] = (bf16_t)f[j].y;
                    b[2] = (bf16_t)f[j].z; b[3] = (bf16_t)f[j].w;
                    *(bf16x4*)(xw + se) = b;
                }
                __builtin_amdgcn_sched_barrier(0);
            }
        }

        // ---- epilogue: rs += xQ_frag * x  (D: col=lane&15, row=kg*4+j) ----
        float rs[2][4];
#pragma unroll
        for (int m = 0; m < 2; ++m)
#pragma unroll
            for (int j = 0; j < 4; ++j) rs[m][j] = 0.0f;

#pragma unroll
        for (int pi = 0; pi < 2; ++pi) {
            const int p = pi ? (15 - w) : w;
#pragma unroll
            for (int h = 0; h < 2; ++h) {
                const int c0 = p * 32 + h * 16;
#pragma unroll
                for (int m = 0; m < 2; ++m) {
#pragma unroll
                    for (int j = 0; j < 4; ++j) {
                        int r = m * 16 + kg * 4 + j;
                        int e = (r * FDIM + c0 + col) ^ ((r & 15) << 3);
                        rs[m][j] += acc[pi][h][m][j] * (float)xr[e];
                    }
                }
            }
        }

#pragma unroll
        for (int m = 0; m < 2; ++m) {
#pragma unroll
            for (int j = 0; j < 4; ++j) {
                float v2 = rs[m][j];
                v2 += __shfl_xor(v2, 1);
                v2 += __shfl_xor(v2, 2);
                v2 += __shfl_xor(v2, 4);
                v2 += __shfl_xor(v2, 8);
                rs[m][j] = v2;
            }
        }
        if (col == 0) {
#pragma unroll
            for (int m = 0; m < 2; ++m)
#pragma unroll
                for (int j = 0; j < 4; ++j)
                    rsum[w][m * 16 + kg * 4 + j] = rs[m][j];
        }
        __syncthreads();   // publish rsum (staging writes also done above)

        if (tid < BM) {
            float s = 0.0f;
#pragma unroll
            for (int ww = 0; ww < 8; ++ww) s += rsum[ww][tid];
            out[row0 + tid] = s;
        }
        __syncthreads();   // out-reads of rsum done; next tile may reuse
    }
}

extern "C" void kernel_launch(void* const* d_in, const int* in_sizes, int n_in,
                              void* d_out, int out_size, void* d_ws, size_t ws_size,
                              hipStream_t stream) {
    const float* x = (const float*)d_in[0];
    const float* Q = (const float*)d_in[1];
    float* out = (float*)d_out;
    bf16_t* Qt = (bf16_t*)d_ws;        // 512*512*2 = 512 KB scratch

    dim3 tgrid(FDIM / 32, FDIM / 32);
    qtrans_kernel<<<tgrid, 256, 0, stream>>>(Q, Qt);
    bilinear_kernel<<<NBLK, NTHR, 0, stream>>>(x, Qt, out);
}

// Round 11
// 122.025 us; speedup vs baseline: 1.6517x; 1.6517x over previous
//
#include <hip/hip_runtime.h>
#include <hip/hip_bf16.h>

typedef __bf16 bf16_t;
typedef __bf16 bf16x8 __attribute__((ext_vector_type(8)));
typedef __bf16 bf16x4 __attribute__((ext_vector_type(4)));
typedef float f32x4 __attribute__((ext_vector_type(4)));

#define FDIM 512
#define NTHR 512
#define BROWS 128   // 8 waves x 16 rows
#define NBLK 1024   // 131072 / 128

// Kernel 1: Qt[g][f] = bf16(Q[f][g]) via LDS-tiled transpose
__global__ void qtrans_kernel(const float* __restrict__ Q, bf16_t* __restrict__ Qt) {
    __shared__ float t[32][33];
    int tx = threadIdx.x & 31;
    int ty = threadIdx.x >> 5;
    int f0 = blockIdx.x * 32;
    int g0 = blockIdx.y * 32;
#pragma unroll
    for (int i = 0; i < 4; ++i)
        t[ty + 8 * i][tx] = Q[(size_t)(f0 + ty + 8 * i) * FDIM + g0 + tx];
    __syncthreads();
#pragma unroll
    for (int i = 0; i < 4; ++i)
        Qt[(size_t)(g0 + ty + 8 * i) * FDIM + f0 + tx] = (bf16_t)t[tx][ty + 8 * i];
}

// Kernel 2: out[b] = sum_g (x Q)[b,g] * x[b,g]
// M-SPLIT design: each wave owns 16 rows; x loaded ONCE global->16 static
// a-frags (64 VGPRs). Qt panels (32 cols x 512 k, triangle-trimmed) staged
// L2->LDS double-buffered, shared by all 8 waves. One barrier per panel.
// No x in LDS, no N-split, no cross-wave row sharing.
__global__ __launch_bounds__(NTHR, 4) void bilinear_kernel(
    const float* __restrict__ x, const bf16_t* __restrict__ Qt,
    float* __restrict__ out)
{
    __shared__ bf16_t panel[2][32 * FDIM];   // 2 x 32 KB, swz: k ^= (c&15)<<3

    const int tid = threadIdx.x;
    const int w   = tid >> 6;
    const int l   = tid & 63;
    const int col = l & 15;
    const int kg  = l >> 4;

    const int row0w = blockIdx.x * BROWS + w * 16;   // wave's first row

    // ---- A: 16 rows into 16 static a-frags (fenced batches of 4 ks) ----
    const float* arow = x + (size_t)(row0w + col) * FDIM + kg * 8;
    bf16x8 a[16];
#pragma unroll
    for (int ks = 0; ks < 16; ++ks) {
        float4 f0 = *(const float4*)(arow + ks * 32);
        float4 f1 = *(const float4*)(arow + ks * 32 + 4);
        bf16x8 v;
        v[0] = (bf16_t)f0.x; v[1] = (bf16_t)f0.y; v[2] = (bf16_t)f0.z; v[3] = (bf16_t)f0.w;
        v[4] = (bf16_t)f1.x; v[5] = (bf16_t)f1.y; v[6] = (bf16_t)f1.z; v[7] = (bf16_t)f1.w;
        a[ks] = v;
        if ((ks & 3) == 3) __builtin_amdgcn_sched_barrier(0);  // cap live float4s
    }

    // ---- stage panel 0 (cols 0..31, k < 32) ----
    {
        // slot = i*512+tid: c = slot>>6 (i*8+w), kc = slot&63 (=l)
        const int c = w;           // i = 0 only needed for check; do all 4 i's
#pragma unroll
        for (int i = 0; i < 4; ++i) {
            int cc = i * 8 + w;
            if (l < 4) {           // k < 32 for panel 0
                bf16x8 q = *(const bf16x8*)(Qt + (size_t)cc * FDIM + l * 8);
                int e = cc * FDIM + ((l * 8) ^ ((cc & 15) << 3));
                *(bf16x8*)(&panel[0][0] + e) = q;
            }
        }
        (void)c;
    }
    __syncthreads();

    float rs[4] = {0.f, 0.f, 0.f, 0.f};

#pragma unroll 1
    for (int p = 0; p < 16; ++p) {
        const int buf = p & 1;
        const bf16_t* pb = &panel[buf][0];

        // ---- stage panel p+1 into buf^1 (triangle: k < 32*(p+2)) ----
        if (p + 1 < 16) {
            const int pn = p + 1;
            const int lim = 4 * (pn + 1);          // active kc count
            bf16_t* pw = &panel[buf ^ 1][0];
#pragma unroll
            for (int i = 0; i < 4; ++i) {
                int cc = i * 8 + w;
                if (l < lim) {
                    bf16x8 q = *(const bf16x8*)(Qt + (size_t)(pn * 32 + cc) * FDIM + l * 8);
                    int e = cc * FDIM + ((l * 8) ^ ((cc & 15) << 3));
                    *(bf16x8*)(pw + e) = q;
                }
            }
        }

        // ---- compute: 16 rows x 32 cols, k <= 32*(p+1) ----
        f32x4 acc0, acc1;
#pragma unroll
        for (int j = 0; j < 4; ++j) { acc0[j] = 0.f; acc1[j] = 0.f; }

        const int kswz = col << 3;
#pragma unroll
        for (int ks = 0; ks < 16; ++ks) {
            if (ks <= p) {
                int kk = (ks * 32 + kg * 8) ^ kswz;
                bf16x8 b0 = *(const bf16x8*)(pb + col * FDIM + kk);
                bf16x8 b1 = *(const bf16x8*)(pb + (16 + col) * FDIM + kk);
                acc0 = __builtin_amdgcn_mfma_f32_16x16x32_bf16(a[ks], b0, acc0, 0, 0, 0);
                acc1 = __builtin_amdgcn_mfma_f32_16x16x32_bf16(a[ks], b1, acc1, 0, 0, 0);
            }
        }

        // ---- epilogue: rs += xQ_frag * x  (D: col=l&15, row=kg*4+j) ----
        const float* xe = x + (size_t)(row0w + kg * 4) * FDIM + p * 32 + col;
#pragma unroll
        for (int j = 0; j < 4; ++j) {
            float e0 = xe[(size_t)j * FDIM];
            float e1 = xe[(size_t)j * FDIM + 16];
            rs[j] += acc0[j] * e0 + acc1[j] * e1;
        }

        __syncthreads();   // panel p+1 staged; panel p reads done
    }

    // ---- reduce over 16 cols (lanes sharing kg) and store ----
#pragma unroll
    for (int j = 0; j < 4; ++j) {
        float v2 = rs[j];
        v2 += __shfl_xor(v2, 1);
        v2 += __shfl_xor(v2, 2);
        v2 += __shfl_xor(v2, 4);
        v2 += __shfl_xor(v2, 8);
        rs[j] = v2;
    }
    if (col == 0) {
#pragma unroll
        for (int j = 0; j < 4; ++j)
            out[row0w + kg * 4 + j] = rs[j];
    }
}

extern "C" void kernel_launch(void* const* d_in, const int* in_sizes, int n_in,
                              void* d_out, int out_size, void* d_ws, size_t ws_size,
                              hipStream_t stream) {
    const float* x = (const float*)d_in[0];
    const float* Q = (const float*)d_in[1];
    float* out = (float*)d_out;
    bf16_t* Qt = (bf16_t*)d_ws;        // 512*512*2 = 512 KB scratch

    dim3 tgrid(FDIM / 32, FDIM / 32);
    qtrans_kernel<<<tgrid, 256, 0, stream>>>(Q, Qt);
    bilinear_kernel<<<NBLK, NTHR, 0, stream>>>(x, Qt, out);
}